// Round 1
// baseline (554.026 us; speedup 1.0000x reference)
//
#include <hip/hip_runtime.h>
#include <hip/hip_bf16.h>

#define NN 100000
#define NE 1250000
#define DD 64
#define RR 16
#define NTILE 6250        // NN/16 dst-tiles
#define NBINS 100000      // (dst>>4)*16 + rel
#define NBLK_SCAN 391     // ceil(NBINS/256)
#define CAPROWS 256       // staged x-rows per tile (Poisson(200): P(cnt>256)~3e-5, fallback kept)
#define ROWB 144          // LDS row stride bytes: 36 words -> bank rotation, conflict-free
#define DLCAP 576         // staged dst-local bytes (P(cnt>576)~0, shuffle fallback kept)

typedef __attribute__((ext_vector_type(8))) short s16x8;
typedef __attribute__((ext_vector_type(4))) float f32x4;

static __device__ __forceinline__ unsigned short f2bf(float v) {
    __hip_bfloat16 h = __float2bfloat16(v);
    return __builtin_bit_cast(unsigned short, h);
}
static __device__ __forceinline__ unsigned int pack2(float a, float b) {
    return ((unsigned int)f2bf(b) << 16) | (unsigned int)f2bf(a);
}

// ---------------- sort edges by (dst-tile, rel): counting sort, 100k bins ----------------

__global__ void hist_key(const int* __restrict__ dst, const int* __restrict__ et,
                         int* __restrict__ cnt) {
    int e = blockIdx.x * 256 + threadIdx.x;
    if (e < NE) atomicAdd(&cnt[(dst[e] >> 4) * 16 + et[e]], 1);
}

__global__ __launch_bounds__(256) void scan1(const int* __restrict__ cnt,
                                             int* __restrict__ rp, int* __restrict__ part) {
    __shared__ int s[256];
    int i = blockIdx.x * 256 + threadIdx.x;
    int v = (i < NBINS) ? cnt[i] : 0;
    s[threadIdx.x] = v;
    __syncthreads();
    for (int off = 1; off < 256; off <<= 1) {
        int t = (threadIdx.x >= off) ? s[threadIdx.x - off] : 0;
        __syncthreads();
        s[threadIdx.x] += t;
        __syncthreads();
    }
    if (i < NBINS) rp[i] = s[threadIdx.x] - v;        // exclusive
    if (threadIdx.x == 255) part[blockIdx.x] = s[255];
}

__global__ void scan2(int* __restrict__ part, int* __restrict__ rp) {
    __shared__ int s[NBLK_SCAN];
    if (threadIdx.x < NBLK_SCAN) s[threadIdx.x] = part[threadIdx.x];
    __syncthreads();
    if (threadIdx.x == 0) {
        int acc = 0;
        for (int b = 0; b < NBLK_SCAN; ++b) { int t = s[b]; s[b] = acc; acc += t; }
        rp[NBINS] = NE;
    }
    __syncthreads();
    if (threadIdx.x < NBLK_SCAN) part[threadIdx.x] = s[threadIdx.x];
}

__global__ void scan3(int* __restrict__ rp, const int* __restrict__ part, int* __restrict__ cur) {
    int i = blockIdx.x * 256 + threadIdx.x;
    if (i < NBINS) {
        int v = rp[i] + part[blockIdx.x];
        rp[i] = v;
        cur[i] = v;
    }
}

// ep[p] = src | (dst&15)<<20
__global__ void scatter_key(const int* __restrict__ src, const int* __restrict__ dst,
                            const int* __restrict__ et, int* __restrict__ cur,
                            unsigned int* __restrict__ ep) {
    int e = blockIdx.x * 256 + threadIdx.x;
    if (e >= NE) return;
    int d = dst[e];
    int p = atomicAdd(&cur[(d >> 4) * 16 + et[e]], 1);
    ep[p] = (unsigned int)src[e] | ((unsigned int)(d & 15) << 20);
}

// ---------------- precision prep ----------------

// wt[l][p][o][d] = bf16( (p<16 ? W_l[p] : sw_l)[d][o] )
__global__ void prep_w2(const float* __restrict__ W1, const float* __restrict__ sw1,
                        const float* __restrict__ W2, const float* __restrict__ sw2,
                        unsigned short* __restrict__ wt) {
    int i = blockIdx.x * 256 + threadIdx.x;
    if (i >= 2 * 17 * DD * DD) return;
    int d = i & 63;
    int o = (i >> 6) & 63;
    int p = (i >> 12) % 17;
    int l = i / (17 * DD * DD);
    const float* srcp;
    if (p < 16) srcp = (l ? W2 : W1) + p * DD * DD;
    else        srcp = (l ? sw2 : sw1);
    wt[i] = f2bf(srcp[d * DD + o]);
}

__global__ void prep_x2(const float* __restrict__ x, unsigned short* __restrict__ xb) {
    int i = blockIdx.x * blockDim.x + threadIdx.x;
    if (i < NN * DD) xb[i] = f2bf(x[i]);
}

// ---------------- fused layer ----------------
// Block = 16-dst tile. Phase 1: bulk-stage the tile's src rows (<=256) into LDS with high MLP
// (144B row stride -> conflict-free staging writes and fragment reads), plus dst-local bytes.
// Phase 2: 4 waves each own a 16-output-channel block (ob = wid) and walk all 17 planes
// (no cross-wave reduction, no Dred, one barrier total, perfectly balanced waves).
// Per (rel) bin, 32-edge superchunks as before; indicator built from staged dl bytes
// (2 dword LDS reads + funnel shift) instead of 8 ds_bpermute. Self plane accumulates
// directly into the fp32 accumulator (C/D layouts identical) - exact, no pack/indicator.
__global__ __launch_bounds__(256, 4) void fused_layer(
    const unsigned short* __restrict__ xb,   // [N][64] bf16 layer input
    const unsigned short* __restrict__ wt,   // [17][64][64] bf16 (o-major, d inner)
    const int* __restrict__ rp,              // [NBINS+1]
    const unsigned int* __restrict__ ep,     // [E] src | dstloc<<20
    const float* __restrict__ bias,
    const float* __restrict__ xres,          // fp32 residual or nullptr
    unsigned short* __restrict__ outb,       // bf16 out (layer 1) or nullptr
    float* __restrict__ outf)                // fp32 out (layer 2) or nullptr
{
    __shared__ __attribute__((aligned(16))) unsigned char Ash[CAPROWS * ROWB]; // 36864 B
    __shared__ __attribute__((aligned(8)))  unsigned char dlb[DLCAP + 32];     //   608 B

    const int tid  = threadIdx.x;
    const int wid  = tid >> 6;
    const int lane = tid & 63;
    const int c = lane & 15;
    const int q = lane >> 4;
    const int tile = blockIdx.x;
    const int n0 = tile * 16;

    const int e0  = rp[tile * 16];
    const int cnt = rp[tile * 16 + 16] - e0;

    // ---- stage dst-local bytes ----
    {
        const int lim = cnt < DLCAP ? cnt : DLCAP;
        for (int i = tid; i < lim; i += 256)
            dlb[i] = (unsigned char)(ep[e0 + i] >> 20);
        if (tid < 32) {
            int p = lim + tid;
            if (p < DLCAP + 32) dlb[p] = 0xFF;   // pad: never matches c (c<16)
        }
    }
    // ---- stage x rows (2 threads/row, 4 independent 16B loads each) ----
    {
        const int nrows = cnt < CAPROWS ? cnt : CAPROWS;
        const int half = tid & 1;
        for (int i = tid >> 1; i < nrows; i += 128) {
            int src = (int)(ep[e0 + i] & 0xFFFFF);
            const unsigned short* xr = xb + (size_t)src * DD + half * 32;
            s16x8 v0 = *(const s16x8*)(xr);
            s16x8 v1 = *(const s16x8*)(xr + 8);
            s16x8 v2 = *(const s16x8*)(xr + 16);
            s16x8 v3 = *(const s16x8*)(xr + 24);
            unsigned char* bp = Ash + i * ROWB + half * 64;
            *(s16x8*)(bp)      = v0;
            *(s16x8*)(bp + 16) = v1;
            *(s16x8*)(bp + 32) = v2;
            *(s16x8*)(bp + 48) = v3;
        }
    }
    __syncthreads();

    const bool dlOK = (cnt <= DLCAP);
    const int och = wid * 16 + c;
    const unsigned short* wbase = wt + (size_t)och * DD + q * 8;
    s16x8 w0 = *(const s16x8*)(wbase);          // plane 0
    s16x8 w1 = *(const s16x8*)(wbase + 32);
    f32x4 Dacc = {0.f, 0.f, 0.f, 0.f};
    const short one = (short)0x3F80;

    for (int r = 0; r < 16; ++r) {
        // prefetch next plane's weights (r=15 prefetches the self plane)
        const unsigned short* nwp = wbase + (size_t)(r + 1) * (DD * DD);
        s16x8 nw0 = *(const s16x8*)(nwp);
        s16x8 nw1 = *(const s16x8*)(nwp + 32);

        const int s0 = rp[tile * 16 + r];
        const int s1 = rp[tile * 16 + r + 1];
        for (int b0 = s0; b0 < s1; b0 += 32) {
            const int rem = s1 - b0;
            const bool hasB = (rem > 16);
            const int lbase = b0 - e0;

            // ---- indicator A2 ----
            s16x8 a2;
            if (dlOK) {
                const unsigned* dl32 = (const unsigned*)dlb;
                int idx = lbase + q * 4;
                int w = idx >> 2;
                int sh = (idx & 3) * 8;
                unsigned long long pa =
                    ((unsigned long long)dl32[w + 1] << 32) | dl32[w];
                unsigned da = (unsigned)(pa >> sh);
                unsigned db = 0;
                if (hasB) {
                    unsigned long long pb =
                        ((unsigned long long)dl32[w + 5] << 32) | dl32[w + 4];
                    db = (unsigned)(pb >> sh);
                }
                #pragma unroll
                for (int j = 0; j < 4; ++j) {
                    int jj = q * 4 + j;
                    a2[j]     = ((int)((da >> (8 * j)) & 255) == c && jj < rem)
                                ? one : (short)0;
                    a2[j + 4] = (hasB && (int)((db >> (8 * j)) & 255) == c && jj < rem - 16)
                                ? one : (short)0;
                }
            } else {
                // huge-tile fallback (cnt > DLCAP, ~never): original shuffle path
                int eA = min(b0 + c, s1 - 1);
                unsigned wa = ep[eA];
                int dlA = (b0 + c < s1) ? (int)(wa >> 20) : 31;
                int dlB = 31;
                if (hasB) {
                    int eB = min(b0 + 16 + c, s1 - 1);
                    unsigned wb = ep[eB];
                    dlB = (b0 + 16 + c < s1) ? (int)(wb >> 20) : 31;
                }
                #pragma unroll
                for (int j = 0; j < 4; ++j) {
                    int dj = __shfl(dlA, q * 4 + j, 64);
                    a2[j] = (dj == c) ? one : (short)0;
                    int djb = __shfl(dlB, q * 4 + j, 64);
                    a2[j + 4] = (hasB && djb == c) ? one : (short)0;
                }
            }

            // ---- A fragments from LDS (global fallback for rows >= CAPROWS) ----
            int rA = min(b0 + c, s1 - 1) - e0;
            s16x8 aA0, aA1;
            if (rA < CAPROWS) {
                const unsigned char* ap = Ash + rA * ROWB + q * 16;
                aA0 = *(const s16x8*)(ap);
                aA1 = *(const s16x8*)(ap + 64);
            } else {
                int srcA = (int)(ep[e0 + rA] & 0xFFFFF);
                const unsigned short* xr = xb + (size_t)srcA * DD + q * 8;
                aA0 = *(const s16x8*)(xr);
                aA1 = *(const s16x8*)(xr + 32);
            }
            s16x8 aB0, aB1;
            if (hasB) {
                int rB = min(b0 + 16 + c, s1 - 1) - e0;
                if (rB < CAPROWS) {
                    const unsigned char* bp = Ash + rB * ROWB + q * 16;
                    aB0 = *(const s16x8*)(bp);
                    aB1 = *(const s16x8*)(bp + 64);
                } else {
                    int srcB = (int)(ep[e0 + rB] & 0xFFFFF);
                    const unsigned short* xr = xb + (size_t)srcB * DD + q * 8;
                    aB0 = *(const s16x8*)(xr);
                    aB1 = *(const s16x8*)(xr + 32);
                }
            }

            __builtin_amdgcn_s_setprio(1);
            f32x4 cA = {0.f, 0.f, 0.f, 0.f};
            cA = __builtin_amdgcn_mfma_f32_16x16x32_bf16(aA0, w0, cA, 0, 0, 0);
            cA = __builtin_amdgcn_mfma_f32_16x16x32_bf16(aA1, w1, cA, 0, 0, 0);
            s16x8 b2v;
            if (hasB) {
                f32x4 cB = {0.f, 0.f, 0.f, 0.f};
                cB = __builtin_amdgcn_mfma_f32_16x16x32_bf16(aB0, w0, cB, 0, 0, 0);
                cB = __builtin_amdgcn_mfma_f32_16x16x32_bf16(aB1, w1, cB, 0, 0, 0);
                #pragma unroll
                for (int j = 0; j < 4; ++j) {
                    b2v[j]     = (short)f2bf(cA[j]);
                    b2v[j + 4] = (short)f2bf(cB[j]);
                }
            } else {
                #pragma unroll
                for (int j = 0; j < 4; ++j) {
                    b2v[j]     = (short)f2bf(cA[j]);
                    b2v[j + 4] = 0;
                }
            }
            Dacc = __builtin_amdgcn_mfma_f32_16x16x32_bf16(a2, b2v, Dacc, 0, 0, 0);
            __builtin_amdgcn_s_setprio(0);
        }
        w0 = nw0; w1 = nw1;
    }

    // ---- self plane (w0,w1 now hold plane 16): exact fp32 accumulate, no indicator ----
    {
        const unsigned short* xr = xb + (size_t)(n0 + c) * DD + q * 8;
        s16x8 a0 = *(const s16x8*)(xr);
        s16x8 a1 = *(const s16x8*)(xr + 32);
        Dacc = __builtin_amdgcn_mfma_f32_16x16x32_bf16(a0, w0, Dacc, 0, 0, 0);
        Dacc = __builtin_amdgcn_mfma_f32_16x16x32_bf16(a1, w1, Dacc, 0, 0, 0);
    }

    // ---- epilogue: lane (c,q) of wave ob holds node q*4+v, channel ob*16+c ----
    const float bc = bias[och];
    #pragma unroll
    for (int v = 0; v < 4; ++v) {
        const int node = n0 + q * 4 + v;
        float val = Dacc[v] + bc;
        if (xres) val += xres[(size_t)node * DD + och];
        val = fmaxf(val, 0.f);
        if (outf) outf[(size_t)node * DD + och] = val;
        if (outb) {
            float nb = __shfl_xor(val, 1, 64);
            if (!(c & 1))
                *(unsigned int*)(outb + (size_t)node * DD + och) = pack2(val, nb);
        }
    }
}

// ================= launch =================

extern "C" void kernel_launch(void* const* d_in, const int* in_sizes, int n_in,
                              void* d_out, int out_size, void* d_ws, size_t ws_size,
                              hipStream_t stream)
{
    (void)in_sizes; (void)n_in; (void)out_size; (void)ws_size;
    const float* x    = (const float*)d_in[0];
    const int*   ei   = (const int*)d_in[1];
    const int*   et   = (const int*)d_in[2];
    const float* W1   = (const float*)d_in[3];
    const float* sw1  = (const float*)d_in[4];
    const float* b1   = (const float*)d_in[5];
    const float* W2   = (const float*)d_in[6];
    const float* sw2  = (const float*)d_in[7];
    const float* b2   = (const float*)d_in[8];
    float* out = (float*)d_out;

    const int* srcA = ei;
    const int* dstA = ei + NE;

    char* ws = (char*)d_ws;
    unsigned short* xb   = (unsigned short*)(ws);                 // 12,800,000
    unsigned short* h1b  = (unsigned short*)(ws + 12800000);      // 12,800,000
    unsigned short* wt2  = (unsigned short*)(ws + 25600000);      //    278,528
    unsigned int*   ep   = (unsigned int*)(ws + 25878528);        //  5,000,000
    int*            rp   = (int*)(ws + 30878528);                 //    400,004
    int*            cnt  = (int*)(ws + 31278544);                 //    400,000
    int*            cur  = (int*)(ws + 31678544);                 //    400,000
    int*            part = (int*)(ws + 32078544);                 //      1,600

    const int NB_E    = (NE + 255) / 256;        // 4883
    const int NB_ELEM = (NN * DD + 255) / 256;   // 25000
    const int WPL = 17 * DD * DD;                // wt2 per-layer stride

    // sort edges by (dst-tile, rel) — once, reused by both layers
    hipMemsetAsync(cnt, 0, NBINS * sizeof(int), stream);
    hist_key<<<NB_E, 256, 0, stream>>>(dstA, et, cnt);
    scan1<<<NBLK_SCAN, 256, 0, stream>>>(cnt, rp, part);
    scan2<<<1, 512, 0, stream>>>(part, rp);
    scan3<<<NBLK_SCAN, 256, 0, stream>>>(rp, part, cur);
    scatter_key<<<NB_E, 256, 0, stream>>>(srcA, dstA, et, cur, ep);

    // precision prep
    prep_w2<<<(2 * 17 * DD * DD + 255) / 256, 256, 0, stream>>>(W1, sw1, W2, sw2, wt2);
    prep_x2<<<NB_ELEM, 256, 0, stream>>>(x, xb);

    // ---- layer 1 (residual) ----
    fused_layer<<<NTILE, 256, 0, stream>>>(xb, wt2, rp, ep, b1, x, h1b, nullptr);
    // ---- layer 2 (no residual) ----
    fused_layer<<<NTILE, 256, 0, stream>>>(h1b, wt2 + WPL, rp, ep, b2, nullptr, nullptr, out);
}

// Round 2
// 528.970 us; speedup vs baseline: 1.0474x; 1.0474x over previous
//
#include <hip/hip_runtime.h>
#include <hip/hip_bf16.h>

#define NN 100000
#define NE 1250000
#define DD 64
#define RR 16
#define NTILE 6250        // NN/16 dst-tiles
#define NBINS 100000      // (dst>>4)*16 + rel
#define NBLK_SCAN 391     // ceil(NBINS/256)
#define CAPROWS 224       // staged x-rows per tile (mean 200, sd 14 -> ~4% tiles overflow a few rows, global fallback)
#define DLCAP 576         // staged dst-local bytes (P(cnt>576)~0, shuffle fallback kept)

typedef __attribute__((ext_vector_type(8))) short s16x8;
typedef __attribute__((ext_vector_type(4))) float f32x4;

static __device__ __forceinline__ unsigned short f2bf(float v) {
    __hip_bfloat16 h = __float2bfloat16(v);
    return __builtin_bit_cast(unsigned short, h);
}
static __device__ __forceinline__ unsigned int pack2(float a, float b) {
    return ((unsigned int)f2bf(b) << 16) | (unsigned int)f2bf(a);
}

// ---------------- sort edges by (dst-tile, rel): counting sort, 100k bins ----------------

__global__ void hist_key(const int* __restrict__ dst, const int* __restrict__ et,
                         int* __restrict__ cnt) {
    int e = blockIdx.x * 256 + threadIdx.x;
    if (e < NE) atomicAdd(&cnt[(dst[e] >> 4) * 16 + et[e]], 1);
}

__global__ __launch_bounds__(256) void scan1(const int* __restrict__ cnt,
                                             int* __restrict__ rp, int* __restrict__ part) {
    __shared__ int s[256];
    int i = blockIdx.x * 256 + threadIdx.x;
    int v = (i < NBINS) ? cnt[i] : 0;
    s[threadIdx.x] = v;
    __syncthreads();
    for (int off = 1; off < 256; off <<= 1) {
        int t = (threadIdx.x >= off) ? s[threadIdx.x - off] : 0;
        __syncthreads();
        s[threadIdx.x] += t;
        __syncthreads();
    }
    if (i < NBINS) rp[i] = s[threadIdx.x] - v;        // exclusive
    if (threadIdx.x == 255) part[blockIdx.x] = s[255];
}

__global__ void scan2(int* __restrict__ part, int* __restrict__ rp) {
    __shared__ int s[NBLK_SCAN];
    if (threadIdx.x < NBLK_SCAN) s[threadIdx.x] = part[threadIdx.x];
    __syncthreads();
    if (threadIdx.x == 0) {
        int acc = 0;
        for (int b = 0; b < NBLK_SCAN; ++b) { int t = s[b]; s[b] = acc; acc += t; }
        rp[NBINS] = NE;
    }
    __syncthreads();
    if (threadIdx.x < NBLK_SCAN) part[threadIdx.x] = s[threadIdx.x];
}

__global__ void scan3(int* __restrict__ rp, const int* __restrict__ part, int* __restrict__ cur) {
    int i = blockIdx.x * 256 + threadIdx.x;
    if (i < NBINS) {
        int v = rp[i] + part[blockIdx.x];
        rp[i] = v;
        cur[i] = v;
    }
}

// ep[p] = src | (dst&15)<<20
__global__ void scatter_key(const int* __restrict__ src, const int* __restrict__ dst,
                            const int* __restrict__ et, int* __restrict__ cur,
                            unsigned int* __restrict__ ep) {
    int e = blockIdx.x * 256 + threadIdx.x;
    if (e >= NE) return;
    int d = dst[e];
    int p = atomicAdd(&cur[(d >> 4) * 16 + et[e]], 1);
    ep[p] = (unsigned int)src[e] | ((unsigned int)(d & 15) << 20);
}

// ---------------- precision prep ----------------

// wt[l][p][o][d] = bf16( (p<16 ? W_l[p] : sw_l)[d][o] )
__global__ void prep_w2(const float* __restrict__ W1, const float* __restrict__ sw1,
                        const float* __restrict__ W2, const float* __restrict__ sw2,
                        unsigned short* __restrict__ wt) {
    int i = blockIdx.x * 256 + threadIdx.x;
    if (i >= 2 * 17 * DD * DD) return;
    int d = i & 63;
    int o = (i >> 6) & 63;
    int p = (i >> 12) % 17;
    int l = i / (17 * DD * DD);
    const float* srcp;
    if (p < 16) srcp = (l ? W2 : W1) + p * DD * DD;
    else        srcp = (l ? sw2 : sw1);
    wt[i] = f2bf(srcp[d * DD + o]);
}

__global__ void prep_x2(const float* __restrict__ x, unsigned short* __restrict__ xb) {
    int i = blockIdx.x * blockDim.x + threadIdx.x;
    if (i < NN * DD) xb[i] = f2bf(x[i]);
}

// ---------------- fused layer ----------------
// Block = 16-dst tile. Phase 1: bulk-stage the tile's src rows (<=224) into LDS with high MLP.
// Row = one 128B stripe; 16B chunk s of row i stored at slot (s ^ (i&7))  [XOR swizzle].
// Quarter-phase analysis (fixed q, c=0..15): slot = q ^ ((base+c)&7) covers all 8 slots
// exactly twice -> 2-way per phase -> conflict-free (m136: 2-way is free). Same for writes.
// Phase 2: 4 waves each own a 16-output-channel block (ob = wid) and walk all 17 planes
// (no cross-wave reduction, one barrier total, balanced waves). Indicator from staged
// dst-local bytes. Self plane accumulates directly into the fp32 accumulator.
__global__ __launch_bounds__(256, 5) void fused_layer(
    const unsigned short* __restrict__ xb,   // [N][64] bf16 layer input
    const unsigned short* __restrict__ wt,   // [17][64][64] bf16 (o-major, d inner)
    const int* __restrict__ rp,              // [NBINS+1]
    const unsigned int* __restrict__ ep,     // [E] src | dstloc<<20
    const float* __restrict__ bias,
    const float* __restrict__ xres,          // fp32 residual or nullptr
    unsigned short* __restrict__ outb,       // bf16 out (layer 1) or nullptr
    float* __restrict__ outf)                // fp32 out (layer 2) or nullptr
{
    __shared__ __attribute__((aligned(16))) unsigned char Ash[CAPROWS * 128]; // 28672 B
    __shared__ __attribute__((aligned(8)))  unsigned char dlb[DLCAP + 32];    //   608 B

    const int tid  = threadIdx.x;
    const int wid  = tid >> 6;
    const int lane = tid & 63;
    const int c = lane & 15;
    const int q = lane >> 4;
    const int tile = blockIdx.x;
    const int n0 = tile * 16;

    const int e0  = rp[tile * 16];
    const int cnt = rp[tile * 16 + 16] - e0;

    // ---- stage dst-local bytes ----
    {
        const int lim = cnt < DLCAP ? cnt : DLCAP;
        for (int i = tid; i < lim; i += 256)
            dlb[i] = (unsigned char)(ep[e0 + i] >> 20);
        if (tid < 32) {
            int p = lim + tid;
            if (p < DLCAP + 32) dlb[p] = 0xFF;   // pad: never matches c (c<16)
        }
    }
    // ---- stage x rows (2 threads/row, 4 independent 16B loads each), XOR-swizzled slots ----
    {
        const int nrows = cnt < CAPROWS ? cnt : CAPROWS;
        const int half = tid & 1;
        for (int i = tid >> 1; i < nrows; i += 128) {
            int src = (int)(ep[e0 + i] & 0xFFFFF);
            const unsigned short* xr = xb + (size_t)src * DD + half * 32;
            s16x8 v0 = *(const s16x8*)(xr);
            s16x8 v1 = *(const s16x8*)(xr + 8);
            s16x8 v2 = *(const s16x8*)(xr + 16);
            s16x8 v3 = *(const s16x8*)(xr + 24);
            unsigned char* bp = Ash + i * 128;
            const int h8 = (i & 7);
            *(s16x8*)(bp + (((half * 4 + 0) ^ h8) * 16)) = v0;
            *(s16x8*)(bp + (((half * 4 + 1) ^ h8) * 16)) = v1;
            *(s16x8*)(bp + (((half * 4 + 2) ^ h8) * 16)) = v2;
            *(s16x8*)(bp + (((half * 4 + 3) ^ h8) * 16)) = v3;
        }
    }
    __syncthreads();

    const bool dlOK = (cnt <= DLCAP);
    const int och = wid * 16 + c;
    const unsigned short* wbase = wt + (size_t)och * DD + q * 8;
    s16x8 w0 = *(const s16x8*)(wbase);          // plane 0
    s16x8 w1 = *(const s16x8*)(wbase + 32);
    f32x4 Dacc = {0.f, 0.f, 0.f, 0.f};
    const short one = (short)0x3F80;

    for (int r = 0; r < 16; ++r) {
        // prefetch next plane's weights (r=15 prefetches the self plane)
        const unsigned short* nwp = wbase + (size_t)(r + 1) * (DD * DD);
        s16x8 nw0 = *(const s16x8*)(nwp);
        s16x8 nw1 = *(const s16x8*)(nwp + 32);

        const int s0 = rp[tile * 16 + r];
        const int s1 = rp[tile * 16 + r + 1];
        for (int b0 = s0; b0 < s1; b0 += 32) {
            const int rem = s1 - b0;
            const bool hasB = (rem > 16);
            const int lbase = b0 - e0;

            // ---- indicator A2 ----
            s16x8 a2;
            if (dlOK) {
                const unsigned* dl32 = (const unsigned*)dlb;
                int idx = lbase + q * 4;
                int w = idx >> 2;
                int sh = (idx & 3) * 8;
                unsigned long long pa =
                    ((unsigned long long)dl32[w + 1] << 32) | dl32[w];
                unsigned da = (unsigned)(pa >> sh);
                unsigned db = 0;
                if (hasB) {
                    unsigned long long pb =
                        ((unsigned long long)dl32[w + 5] << 32) | dl32[w + 4];
                    db = (unsigned)(pb >> sh);
                }
                #pragma unroll
                for (int j = 0; j < 4; ++j) {
                    int jj = q * 4 + j;
                    a2[j]     = ((int)((da >> (8 * j)) & 255) == c && jj < rem)
                                ? one : (short)0;
                    a2[j + 4] = (hasB && (int)((db >> (8 * j)) & 255) == c && jj < rem - 16)
                                ? one : (short)0;
                }
            } else {
                // huge-tile fallback (cnt > DLCAP, ~never): original shuffle path
                int eA = min(b0 + c, s1 - 1);
                unsigned wa = ep[eA];
                int dlA = (b0 + c < s1) ? (int)(wa >> 20) : 31;
                int dlB = 31;
                if (hasB) {
                    int eB = min(b0 + 16 + c, s1 - 1);
                    unsigned wb = ep[eB];
                    dlB = (b0 + 16 + c < s1) ? (int)(wb >> 20) : 31;
                }
                #pragma unroll
                for (int j = 0; j < 4; ++j) {
                    int dj = __shfl(dlA, q * 4 + j, 64);
                    a2[j] = (dj == c) ? one : (short)0;
                    int djb = __shfl(dlB, q * 4 + j, 64);
                    a2[j + 4] = (hasB && djb == c) ? one : (short)0;
                }
            }

            // ---- A fragments from LDS, XOR-swizzled (global fallback for rows >= CAPROWS) ----
            int rA = min(b0 + c, s1 - 1) - e0;
            s16x8 aA0, aA1;
            if (rA < CAPROWS) {
                const unsigned char* ap = Ash + rA * 128;
                const int off = (q ^ (rA & 7)) * 16;
                aA0 = *(const s16x8*)(ap + off);
                aA1 = *(const s16x8*)(ap + (off ^ 64));
            } else {
                int srcA = (int)(ep[e0 + rA] & 0xFFFFF);
                const unsigned short* xr = xb + (size_t)srcA * DD + q * 8;
                aA0 = *(const s16x8*)(xr);
                aA1 = *(const s16x8*)(xr + 32);
            }
            s16x8 aB0, aB1;
            if (hasB) {
                int rB = min(b0 + 16 + c, s1 - 1) - e0;
                if (rB < CAPROWS) {
                    const unsigned char* bp = Ash + rB * 128;
                    const int off = (q ^ (rB & 7)) * 16;
                    aB0 = *(const s16x8*)(bp + off);
                    aB1 = *(const s16x8*)(bp + (off ^ 64));
                } else {
                    int srcB = (int)(ep[e0 + rB] & 0xFFFFF);
                    const unsigned short* xr = xb + (size_t)srcB * DD + q * 8;
                    aB0 = *(const s16x8*)(xr);
                    aB1 = *(const s16x8*)(xr + 32);
                }
            }

            __builtin_amdgcn_s_setprio(1);
            f32x4 cA = {0.f, 0.f, 0.f, 0.f};
            cA = __builtin_amdgcn_mfma_f32_16x16x32_bf16(aA0, w0, cA, 0, 0, 0);
            cA = __builtin_amdgcn_mfma_f32_16x16x32_bf16(aA1, w1, cA, 0, 0, 0);
            s16x8 b2v;
            if (hasB) {
                f32x4 cB = {0.f, 0.f, 0.f, 0.f};
                cB = __builtin_amdgcn_mfma_f32_16x16x32_bf16(aB0, w0, cB, 0, 0, 0);
                cB = __builtin_amdgcn_mfma_f32_16x16x32_bf16(aB1, w1, cB, 0, 0, 0);
                #pragma unroll
                for (int j = 0; j < 4; ++j) {
                    b2v[j]     = (short)f2bf(cA[j]);
                    b2v[j + 4] = (short)f2bf(cB[j]);
                }
            } else {
                #pragma unroll
                for (int j = 0; j < 4; ++j) {
                    b2v[j]     = (short)f2bf(cA[j]);
                    b2v[j + 4] = 0;
                }
            }
            Dacc = __builtin_amdgcn_mfma_f32_16x16x32_bf16(a2, b2v, Dacc, 0, 0, 0);
            __builtin_amdgcn_s_setprio(0);
        }
        w0 = nw0; w1 = nw1;
    }

    // ---- self plane (w0,w1 now hold plane 16): exact fp32 accumulate, no indicator ----
    {
        const unsigned short* xr = xb + (size_t)(n0 + c) * DD + q * 8;
        s16x8 a0 = *(const s16x8*)(xr);
        s16x8 a1 = *(const s16x8*)(xr + 32);
        Dacc = __builtin_amdgcn_mfma_f32_16x16x32_bf16(a0, w0, Dacc, 0, 0, 0);
        Dacc = __builtin_amdgcn_mfma_f32_16x16x32_bf16(a1, w1, Dacc, 0, 0, 0);
    }

    // ---- epilogue: lane (c,q) of wave ob holds node q*4+v, channel ob*16+c ----
    const float bc = bias[och];
    #pragma unroll
    for (int v = 0; v < 4; ++v) {
        const int node = n0 + q * 4 + v;
        float val = Dacc[v] + bc;
        if (xres) val += xres[(size_t)node * DD + och];
        val = fmaxf(val, 0.f);
        if (outf) outf[(size_t)node * DD + och] = val;
        if (outb) {
            float nb = __shfl_xor(val, 1, 64);
            if (!(c & 1))
                *(unsigned int*)(outb + (size_t)node * DD + och) = pack2(val, nb);
        }
    }
}

// ================= launch =================

extern "C" void kernel_launch(void* const* d_in, const int* in_sizes, int n_in,
                              void* d_out, int out_size, void* d_ws, size_t ws_size,
                              hipStream_t stream)
{
    (void)in_sizes; (void)n_in; (void)out_size; (void)ws_size;
    const float* x    = (const float*)d_in[0];
    const int*   ei   = (const int*)d_in[1];
    const int*   et   = (const int*)d_in[2];
    const float* W1   = (const float*)d_in[3];
    const float* sw1  = (const float*)d_in[4];
    const float* b1   = (const float*)d_in[5];
    const float* W2   = (const float*)d_in[6];
    const float* sw2  = (const float*)d_in[7];
    const float* b2   = (const float*)d_in[8];
    float* out = (float*)d_out;

    const int* srcA = ei;
    const int* dstA = ei + NE;

    char* ws = (char*)d_ws;
    unsigned short* xb   = (unsigned short*)(ws);                 // 12,800,000
    unsigned short* h1b  = (unsigned short*)(ws + 12800000);      // 12,800,000
    unsigned short* wt2  = (unsigned short*)(ws + 25600000);      //    278,528
    unsigned int*   ep   = (unsigned int*)(ws + 25878528);        //  5,000,000
    int*            rp   = (int*)(ws + 30878528);                 //    400,004
    int*            cnt  = (int*)(ws + 31278544);                 //    400,000
    int*            cur  = (int*)(ws + 31678544);                 //    400,000
    int*            part = (int*)(ws + 32078544);                 //      1,600

    const int NB_E    = (NE + 255) / 256;        // 4883
    const int NB_ELEM = (NN * DD + 255) / 256;   // 25000
    const int WPL = 17 * DD * DD;                // wt2 per-layer stride

    // sort edges by (dst-tile, rel) — once, reused by both layers
    hipMemsetAsync(cnt, 0, NBINS * sizeof(int), stream);
    hist_key<<<NB_E, 256, 0, stream>>>(dstA, et, cnt);
    scan1<<<NBLK_SCAN, 256, 0, stream>>>(cnt, rp, part);
    scan2<<<1, 512, 0, stream>>>(part, rp);
    scan3<<<NBLK_SCAN, 256, 0, stream>>>(rp, part, cur);
    scatter_key<<<NB_E, 256, 0, stream>>>(srcA, dstA, et, cur, ep);

    // precision prep
    prep_w2<<<(2 * 17 * DD * DD + 255) / 256, 256, 0, stream>>>(W1, sw1, W2, sw2, wt2);
    prep_x2<<<NB_ELEM, 256, 0, stream>>>(x, xb);

    // ---- layer 1 (residual) ----
    fused_layer<<<NTILE, 256, 0, stream>>>(xb, wt2, rp, ep, b1, x, h1b, nullptr);
    // ---- layer 2 (no residual) ----
    fused_layer<<<NTILE, 256, 0, stream>>>(h1b, wt2 + WPL, rp, ep, b2, nullptr, nullptr, out);
}